// Round 11
// baseline (3992.735 us; speedup 1.0000x reference)
//
#include <hip/hip_runtime.h>

typedef unsigned short u16;
typedef unsigned int   u32;

typedef __attribute__((ext_vector_type(8)))  short bf16x8;
typedef __attribute__((ext_vector_type(4)))  float f32x4;
typedef __attribute__((ext_vector_type(8)))  u32   u32x8;
typedef __attribute__((ext_vector_type(16))) float f32x16;

#define B_  32
#define S_  1024
#define NH_ 512
#define G4_ 2048   // 4*NH
#define SC_NWG 8   // scan workgroups on the winning XCD (8 waves each)
#define CAND  256  // election candidates

__device__ __forceinline__ float bf2f(u16 h) {
    return __uint_as_float(((u32)h) << 16);
}
__device__ __forceinline__ u16 f2bf(float f) {
    u32 u = __float_as_uint(f);
    return (u16)((u + 0x7fffu + ((u >> 16) & 1u)) >> 16);
}
__device__ __forceinline__ float fsig(float x) {
    return 1.0f / (1.0f + __expf(-x));
}
__device__ __forceinline__ float ftanh(float x) {
    return 1.0f - 2.0f / (__expf(2.0f * x) + 1.0f);
}

// ---------------- fp32 -> bf16 elementwise convert (vectorized x4) ----------
__global__ void cvt_bf16_kernel(const float* __restrict__ in, u16* __restrict__ out, int n4) {
    int i = blockIdx.x * blockDim.x + threadIdx.x;
    if (i >= n4) return;
    f32x4 v = ((const f32x4*)in)[i];
    unsigned long long pk =
        (unsigned long long)f2bf(v[0]) |
        ((unsigned long long)f2bf(v[1]) << 16) |
        ((unsigned long long)f2bf(v[2]) << 32) |
        ((unsigned long long)f2bf(v[3]) << 48);
    ((unsigned long long*)out)[i] = pk;
}

// ---------------- fp32 [R][C] -> bf16 [C][R] transpose-convert --------------
__global__ void transpose_cvt_kernel(const float* __restrict__ in, u16* __restrict__ out,
                                     int R, int C) {
    __shared__ float tile[32][33];
    int bx = blockIdx.x, by = blockIdx.y;
    int tx = threadIdx.x & 31, ty = threadIdx.x >> 5;
    #pragma unroll
    for (int i = 0; i < 4; i++) {
        int r = by * 32 + ty + i * 8;
        tile[ty + i * 8][tx] = in[(size_t)r * C + bx * 32 + tx];
    }
    __syncthreads();
    #pragma unroll
    for (int i = 0; i < 4; i++) {
        int c = bx * 32 + ty + i * 8;
        out[(size_t)c * R + by * 32 + tx] = f2bf(tile[tx][ty + i * 8]);
    }
}

// ---------------- generic bf16 MFMA GEMM: C = A @ BT^T + bias ---------------
// A [M][K] bf16 row-major, BT [N][K] bf16, bias [N] f32.
// out_mode: 0 -> f32 row-major; 1 -> bf16 in SCAN ORDER [t][wg64][lane][r]
__global__ __launch_bounds__(256) void gemm_bf16_kernel(
    const u16* __restrict__ A, const u16* __restrict__ BT,
    const float* __restrict__ bias, void* __restrict__ Cp,
    int M, int N, int K, int out_mode)
{
    __shared__ u16 Al[128][40];
    __shared__ u16 Bl[128][40];
    int nbm = M >> 7;
    int bm = blockIdx.x % nbm, bn = blockIdx.x / nbm;
    int tid = threadIdx.x, lane = tid & 63, wave = tid >> 6;
    int wr = wave >> 1, wc = wave & 1;
    f32x4 acc[4][4];
    #pragma unroll
    for (int i = 0; i < 4; i++)
        #pragma unroll
        for (int j = 0; j < 4; j++)
            acc[i][j] = (f32x4){0.f, 0.f, 0.f, 0.f};
    int fr  = lane & 15;
    int kof = (lane >> 4) << 3;

    for (int k0 = 0; k0 < K; k0 += 32) {
        __syncthreads();
        #pragma unroll
        for (int i = 0; i < 2; i++) {
            int chunk = i * 256 + tid;
            int r = chunk >> 2, c = (chunk & 3) << 3;
            *(bf16x8*)&Al[r][c] = *(const bf16x8*)&A[(size_t)(bm * 128 + r) * K + k0 + c];
            *(bf16x8*)&Bl[r][c] = *(const bf16x8*)&BT[(size_t)(bn * 128 + r) * K + k0 + c];
        }
        __syncthreads();
        bf16x8 af[4], bfr[4];
        #pragma unroll
        for (int mi = 0; mi < 4; mi++)
            af[mi] = *(const bf16x8*)&Al[wr * 64 + mi * 16 + fr][kof];
        #pragma unroll
        for (int ni = 0; ni < 4; ni++)
            bfr[ni] = *(const bf16x8*)&Bl[wc * 64 + ni * 16 + fr][kof];
        #pragma unroll
        for (int mi = 0; mi < 4; mi++)
            #pragma unroll
            for (int ni = 0; ni < 4; ni++)
                acc[mi][ni] = __builtin_amdgcn_mfma_f32_16x16x32_bf16(af[mi], bfr[ni], acc[mi][ni], 0, 0, 0);
    }
    int rq = lane >> 4;
    #pragma unroll
    for (int mi = 0; mi < 4; mi++) {
        #pragma unroll
        for (int ni = 0; ni < 4; ni++) {
            int n = bn * 128 + wc * 64 + ni * 16 + fr;
            float bv = bias ? bias[n] : 0.f;
            #pragma unroll
            for (int r = 0; r < 4; r++) {
                int m = bm * 128 + wr * 64 + mi * 16 + rq * 4 + r;
                float v = acc[mi][ni][r] + bv;
                if (out_mode == 1) {
                    // scan-order store: [t][wg64][lane2][r2]  (validated round 4)
                    int t = m & 1023, b = m >> 10;
                    int g_loc = n >> 9, wg64i = (n >> 3) & 63, u_loc = n & 7;
                    int lane2 = (((b >> 2) & 1) << 5) | (u_loc << 2) | g_loc;
                    int r2 = (b & 3) | ((b >> 3) << 2);
                    ((u16*)Cp)[(((size_t)t * 64 + wg64i) * 64 + lane2) * 16 + r2] = f2bf(v);
                } else {
                    ((float*)Cp)[(size_t)m * N + n] = v;
                }
            }
        }
    }
}

// ---------------- LSTM scan: 8 same-XCD WGs x 8 waves -----------------------
// Identical protocol to round 10 (validated: scan 3370us, FETCH 66MB):
// election -> intra-XCD L2 messaging; scalar-cache poll (s_dcache_inv +
// s_load_dwordx8, contention-free); one buffer_inv + plain bulk reads.
// ONE change: U fragments are loaded via inline-asm global_load_dwordx4.
// Asm outputs cannot be rematerialized, so the 128 VGPRs stay RESIDENT --
// r10's compiler re-loaded 32x16B/lane from L2 every step (2MB/step on the
// XCD L2, serialized between staging barrier and MFMA).
__global__ __launch_bounds__(512, 2) void lstm_scan_kernel(
    const u16* __restrict__ xw,    // [S][64][64][16] bf16 scan-order
    const u16* __restrict__ UT,    // [4H][NH] bf16
    u16* __restrict__ hseq,        // [B][S][NH] bf16
    u16* __restrict__ hbuf,        // [2][32][512] bf16
    u32* __restrict__ flags,       // [8] per-WG progress
    u32* __restrict__ elect,       // [8] per-XCD registration counters
    int* __restrict__ winner)      // winning XCD id, init -1
{
    __shared__ int s_role;
    __shared__ u16 h_lds[32][520];      // [batch][k], +8 u16 pad (0-conflict, r2)
    __shared__ float gl[8][32][32];     // per-wave gate exchange

    const int tid = threadIdx.x;

    if (tid == 0) {
        u32 xcc;
        asm volatile("s_getreg_b32 %0, hwreg(HW_REG_XCC_ID)" : "=s"(xcc));
        xcc &= 7u;
        u32 r = __hip_atomic_fetch_add(&elect[xcc], 1u,
                    __ATOMIC_ACQ_REL, __HIP_MEMORY_SCOPE_AGENT);
        int role = -1;
        if (r < (u32)SC_NWG) {
            if (r == (u32)SC_NWG - 1) {   // our XCD just reached 8: try claim
                int expv = -1;
                __hip_atomic_compare_exchange_strong(winner, &expv, (int)xcc,
                    __ATOMIC_ACQ_REL, __ATOMIC_ACQUIRE, __HIP_MEMORY_SCOPE_AGENT);
            }
            int w = -1;
            for (int spins = 0; spins < 200000; spins++) {   // bounded
                w = __hip_atomic_load(winner, __ATOMIC_ACQUIRE,
                                      __HIP_MEMORY_SCOPE_AGENT);
                if (w >= 0) break;
                __builtin_amdgcn_s_sleep(8);
            }
            role = (w == (int)xcc) ? (int)r : -1;
        }
        s_role = role;
    }
    __syncthreads();
    const int role = s_role;
    if (role < 0) return;

    const int wave = tid >> 6, lane = tid & 63;
    const int wg64 = role * 8 + wave;
    const int col  = lane & 31, half = lane >> 5;
    const int u_loc = col >> 2, g_loc = col & 3;
    const int ucol  = g_loc * 512 + wg64 * 8 + u_loc;

    // ---- U B-fragments: asm loads -> non-rematerializable -> RESIDENT ----
    bf16x8 ufrag[32];
    {
        const u16* ub = &UT[(size_t)ucol * 512 + half * 8];
        // consecutive kk are 32B apart; 8 blocks of 4 loads, literal offsets
        #define LDU4(i0)                                                      \
            asm volatile(                                                     \
                "global_load_dwordx4 %0, %4, off\n\t"                         \
                "global_load_dwordx4 %1, %4, off offset:32\n\t"               \
                "global_load_dwordx4 %2, %4, off offset:64\n\t"               \
                "global_load_dwordx4 %3, %4, off offset:96"                   \
                : "=&v"(ufrag[i0]), "=&v"(ufrag[i0 + 1]),                     \
                  "=&v"(ufrag[i0 + 2]), "=&v"(ufrag[i0 + 3])                  \
                : "v"(ub + (i0) * 16))
        LDU4(0); LDU4(4); LDU4(8); LDU4(12);
        LDU4(16); LDU4(20); LDU4(24); LDU4(28);
        #undef LDU4
        asm volatile("s_waitcnt vmcnt(0)" ::: "memory");
    }

    float cst[4] = {0.f, 0.f, 0.f, 0.f};

    // h(0) = 0 in LDS (t=0 skips the poll)
    {
        bf16x8 z = (bf16x8){0, 0, 0, 0, 0, 0, 0, 0};
        bf16x8* hf = (bf16x8*)&h_lds[0][0];
        for (int i = tid; i < 2080; i += 512) hf[i] = z;
    }

    const int sb_b  = tid >> 4;   // batch row this thread stages
    const int sb_ic = tid & 15;   // 16B chunk, 256B-strided (0-conflict, r2)

    for (int t = 0; t < 1024; t++) {
        // xw for this step: 32B contiguous per lane, issued early (plain,
        // scalar poll below never drains vmcnt -> latency fully hidden)
        const u16* xp = xw + ((size_t)((size_t)t * 64 + wg64) * 64 + lane) * 16;
        bf16x8 xv0 = *(const bf16x8*)xp;
        bf16x8 xv1 = *(const bf16x8*)(xp + 8);

        if (t > 0) {
            const u32 tg = (u32)t;
            // ---- scalar-cache poll: 1 SMEM op/wave/round, contention-free ----
            {
                u32x8 fv;
                int rounds = 0;
                while (1) {
                    asm volatile("s_dcache_inv\n\t"
                                 "s_load_dwordx8 %0, %1, 0x0\n\t"
                                 "s_waitcnt lgkmcnt(0)"
                                 : "=s"(fv) : "s"(flags) : "memory");
                    bool ok = fv[0] >= tg && fv[1] >= tg && fv[2] >= tg &&
                              fv[3] >= tg && fv[4] >= tg && fv[5] >= tg &&
                              fv[6] >= tg && fv[7] >= tg;
                    if (ok || ++rounds > (1 << 13)) break;
                }
            }
            // one L1 invalidate, then plain bulk reads served by shared L2
            asm volatile("buffer_inv" ::: "memory");
            const char* sbase = (const char*)(hbuf + ((size_t)(t & 1) << 14))
                                + sb_b * 1024 + sb_ic * 16;
            f32x4 r0, r1, r2, r3;
            asm volatile(
                "global_load_dwordx4 %0, %4, off\n\t"
                "global_load_dwordx4 %1, %4, off offset:256\n\t"
                "global_load_dwordx4 %2, %4, off offset:512\n\t"
                "global_load_dwordx4 %3, %4, off offset:768\n\t"
                "s_waitcnt vmcnt(0)"
                : "=&v"(r0), "=&v"(r1), "=&v"(r2), "=&v"(r3)
                : "v"(sbase) : "memory");
            __builtin_amdgcn_sched_barrier(0);
            u16* d = &h_lds[sb_b][sb_ic * 8];
            *(f32x4*)(d)       = r0;
            *(f32x4*)(d + 128) = r1;
            *(f32x4*)(d + 256) = r2;
            *(f32x4*)(d + 384) = r3;
        }
        __syncthreads();

        // gates = h @ Uslice: 2 accumulators halve the dependent-MFMA chain
        f32x16 a0 = {0,0,0,0, 0,0,0,0, 0,0,0,0, 0,0,0,0};
        f32x16 a1 = {0,0,0,0, 0,0,0,0, 0,0,0,0, 0,0,0,0};
        #pragma unroll
        for (int kk = 0; kk < 16; kk++) {
            bf16x8 af0 = *(const bf16x8*)&h_lds[col][kk * 16 + half * 8];
            a0 = __builtin_amdgcn_mfma_f32_32x32x16_bf16(af0, ufrag[kk], a0, 0, 0, 0);
            bf16x8 af1 = *(const bf16x8*)&h_lds[col][(kk + 16) * 16 + half * 8];
            a1 = __builtin_amdgcn_mfma_f32_32x32x16_bf16(af1, ufrag[kk + 16], a1, 0, 0, 0);
        }

        // gate exchange (wave-local LDS; in-wave lgkmcnt ordering, no barrier)
        #pragma unroll
        for (int r = 0; r < 16; r++) {
            int b = (r & 3) + ((r >> 2) << 3) + (half << 2);
            float xwv = bf2f(r < 8 ? (u16)xv0[r] : (u16)xv1[r - 8]);
            gl[wave][b][col] = a0[r] + a1[r] + xwv;
        }

        // cell update: compute 4 results, then burst plain h stores
        u16 hv[4];
        int bi[4];
        #pragma unroll
        for (int i = 0; i < 4; i++) {
            int p = (i << 6) + lane, b = p >> 3, u = p & 7;
            f32x4 g4 = *(const f32x4*)&gl[wave][b][u << 2];   // i,f,g,o
            float si = fsig(g4[0]), sf = fsig(g4[1]);
            float sg = ftanh(g4[2]), so = fsig(g4[3]);
            float c = sf * cst[i] + si * sg;
            cst[i] = c;
            hv[i] = f2bf(so * ftanh(c));
            bi[i] = b;
        }
        u16* hb_out = hbuf + ((size_t)(((size_t)t + 1) & 1) << 14);
        const int j = (wg64 << 3);
        #pragma unroll
        for (int i = 0; i < 4; i++) {
            int p = (i << 6) + lane, u = p & 7;
            u32 hw = hv[i];
            u16* hp = hb_out + bi[i] * 512 + j + u;
            asm volatile("global_store_short %0, %1, off"
                         :: "v"(hp), "v"(hw) : "memory");
        }
        // drain to shared L2 (~300cy), WG barrier, publish per-WG flag
        asm volatile("s_waitcnt vmcnt(0)" ::: "memory");
        __syncthreads();
        if (tid == 0) {
            u32 fv = (u32)(t + 1);
            u32* fq = flags + role;
            asm volatile("global_store_dword %0, %1, off"
                         :: "v"(fq), "v"(fv) : "memory");
        }
        // hseq: plain cached stores, off the critical path
        #pragma unroll
        for (int i = 0; i < 4; i++) {
            int p = (i << 6) + lane, u = p & 7;
            hseq[((size_t)bi[i] * S_ + t) * NH_ + j + u] = hv[i];
        }
    }
}

extern "C" void kernel_launch(void* const* d_in, const int* in_sizes, int n_in,
                              void* d_out, int out_size, void* d_ws, size_t ws_size,
                              hipStream_t stream) {
    const float* x        = (const float*)d_in[0];
    const float* W        = (const float*)d_in[1];
    const float* U        = (const float*)d_in[2];
    const float* hid_bias = (const float*)d_in[3];
    const float* V        = (const float*)d_in[4];
    const float* out_bias = (const float*)d_in[5];

    char* ws = (char*)d_ws;
    size_t off = 0;
    auto carve = [&](size_t bytes) -> void* {
        void* p = ws + off;
        off += (bytes + 255) & ~(size_t)255;
        return p;
    };
    u16* xw     = (u16*)carve((size_t)B_ * S_ * G4_ * 2);   // 128 MB, scan-order
    u16* xbf    = (u16*)carve((size_t)B_ * S_ * NH_ * 2);   //  32 MB
    u16* hseq   = (u16*)carve((size_t)B_ * S_ * NH_ * 2);   //  32 MB
    u16* WT     = (u16*)carve((size_t)G4_ * NH_ * 2);       //   2 MB
    u16* UT     = (u16*)carve((size_t)G4_ * NH_ * 2);       //   2 MB
    u16* VT     = (u16*)carve((size_t)NH_ * NH_ * 2);       // 512 KB
    u16* hbuf   = (u16*)carve((size_t)2 * B_ * NH_ * 2);    //  64 KB
    u32* flags  = (u32*)carve(256);
    u32* elect  = (u32*)carve(256);
    int* winner = (int*)carve(256);

    hipMemsetAsync(flags, 0, 256, stream);
    hipMemsetAsync(elect, 0, 256, stream);
    hipMemsetAsync(winner, 0xFF, 256, stream);   // winner = -1

    int n4 = B_ * S_ * NH_ / 4;
    cvt_bf16_kernel<<<(n4 + 255) / 256, 256, 0, stream>>>(x, xbf, n4);
    transpose_cvt_kernel<<<dim3(G4_ / 32, NH_ / 32), 256, 0, stream>>>(W, WT, NH_, G4_);
    transpose_cvt_kernel<<<dim3(G4_ / 32, NH_ / 32), 256, 0, stream>>>(U, UT, NH_, G4_);
    transpose_cvt_kernel<<<dim3(NH_ / 32, NH_ / 32), 256, 0, stream>>>(V, VT, NH_, NH_);

    // xW + hid_bias -> bf16, stored in scan order
    gemm_bf16_kernel<<<4096, 256, 0, stream>>>(xbf, WT, hid_bias, xw,
                                               B_ * S_, G4_, NH_, 1);
    // sequential LSTM scan (same-XCD election inside)
    lstm_scan_kernel<<<CAND, 512, 0, stream>>>(xw, UT, hseq, hbuf,
                                               flags, elect, winner);
    // out = hseq @ V + out_bias -> f32
    gemm_bf16_kernel<<<1024, 256, 0, stream>>>(hseq, VT, out_bias, d_out,
                                               B_ * S_, NH_, NH_, 0);
}

// Round 12
// 3243.599 us; speedup vs baseline: 1.2310x; 1.2310x over previous
//
#include <hip/hip_runtime.h>

typedef unsigned short u16;
typedef unsigned int   u32;

typedef __attribute__((ext_vector_type(8)))  short bf16x8;
typedef __attribute__((ext_vector_type(4)))  float f32x4;
typedef __attribute__((ext_vector_type(8)))  u32   u32x8;
typedef __attribute__((ext_vector_type(16))) float f32x16;

#define B_  32
#define S_  1024
#define NH_ 512
#define G4_ 2048   // 4*NH
#define SC_NWG 16  // scan workgroups on the winning XCD (4 waves each)
#define CAND  256  // election candidates (~1 per CU at 88KB LDS)

__device__ __forceinline__ float bf2f(u16 h) {
    return __uint_as_float(((u32)h) << 16);
}
__device__ __forceinline__ u16 f2bf(float f) {
    u32 u = __float_as_uint(f);
    return (u16)((u + 0x7fffu + ((u >> 16) & 1u)) >> 16);
}
__device__ __forceinline__ float fsig(float x) {
    return 1.0f / (1.0f + __expf(-x));
}
__device__ __forceinline__ float ftanh(float x) {
    return 1.0f - 2.0f / (__expf(2.0f * x) + 1.0f);
}

// ---------------- fp32 -> bf16 elementwise convert (vectorized x4) ----------
__global__ void cvt_bf16_kernel(const float* __restrict__ in, u16* __restrict__ out, int n4) {
    int i = blockIdx.x * blockDim.x + threadIdx.x;
    if (i >= n4) return;
    f32x4 v = ((const f32x4*)in)[i];
    unsigned long long pk =
        (unsigned long long)f2bf(v[0]) |
        ((unsigned long long)f2bf(v[1]) << 16) |
        ((unsigned long long)f2bf(v[2]) << 32) |
        ((unsigned long long)f2bf(v[3]) << 48);
    ((unsigned long long*)out)[i] = pk;
}

// ---------------- fp32 [R][C] -> bf16 [C][R] transpose-convert --------------
__global__ void transpose_cvt_kernel(const float* __restrict__ in, u16* __restrict__ out,
                                     int R, int C) {
    __shared__ float tile[32][33];
    int bx = blockIdx.x, by = blockIdx.y;
    int tx = threadIdx.x & 31, ty = threadIdx.x >> 5;
    #pragma unroll
    for (int i = 0; i < 4; i++) {
        int r = by * 32 + ty + i * 8;
        tile[ty + i * 8][tx] = in[(size_t)r * C + bx * 32 + tx];
    }
    __syncthreads();
    #pragma unroll
    for (int i = 0; i < 4; i++) {
        int c = bx * 32 + ty + i * 8;
        out[(size_t)c * R + by * 32 + tx] = f2bf(tile[tx][ty + i * 8]);
    }
}

// ---------------- generic bf16 MFMA GEMM: C = A @ BT^T + bias ---------------
// A [M][K] bf16 row-major, BT [N][K] bf16, bias [N] f32.
// out_mode: 0 -> f32 row-major; 1 -> bf16 in SCAN ORDER [t][wg64][lane][r]
__global__ __launch_bounds__(256) void gemm_bf16_kernel(
    const u16* __restrict__ A, const u16* __restrict__ BT,
    const float* __restrict__ bias, void* __restrict__ Cp,
    int M, int N, int K, int out_mode)
{
    __shared__ u16 Al[128][40];
    __shared__ u16 Bl[128][40];
    int nbm = M >> 7;
    int bm = blockIdx.x % nbm, bn = blockIdx.x / nbm;
    int tid = threadIdx.x, lane = tid & 63, wave = tid >> 6;
    int wr = wave >> 1, wc = wave & 1;
    f32x4 acc[4][4];
    #pragma unroll
    for (int i = 0; i < 4; i++)
        #pragma unroll
        for (int j = 0; j < 4; j++)
            acc[i][j] = (f32x4){0.f, 0.f, 0.f, 0.f};
    int fr  = lane & 15;
    int kof = (lane >> 4) << 3;

    for (int k0 = 0; k0 < K; k0 += 32) {
        __syncthreads();
        #pragma unroll
        for (int i = 0; i < 2; i++) {
            int chunk = i * 256 + tid;
            int r = chunk >> 2, c = (chunk & 3) << 3;
            *(bf16x8*)&Al[r][c] = *(const bf16x8*)&A[(size_t)(bm * 128 + r) * K + k0 + c];
            *(bf16x8*)&Bl[r][c] = *(const bf16x8*)&BT[(size_t)(bn * 128 + r) * K + k0 + c];
        }
        __syncthreads();
        bf16x8 af[4], bfr[4];
        #pragma unroll
        for (int mi = 0; mi < 4; mi++)
            af[mi] = *(const bf16x8*)&Al[wr * 64 + mi * 16 + fr][kof];
        #pragma unroll
        for (int ni = 0; ni < 4; ni++)
            bfr[ni] = *(const bf16x8*)&Bl[wc * 64 + ni * 16 + fr][kof];
        #pragma unroll
        for (int mi = 0; mi < 4; mi++)
            #pragma unroll
            for (int ni = 0; ni < 4; ni++)
                acc[mi][ni] = __builtin_amdgcn_mfma_f32_16x16x32_bf16(af[mi], bfr[ni], acc[mi][ni], 0, 0, 0);
    }
    int rq = lane >> 4;
    #pragma unroll
    for (int mi = 0; mi < 4; mi++) {
        #pragma unroll
        for (int ni = 0; ni < 4; ni++) {
            int n = bn * 128 + wc * 64 + ni * 16 + fr;
            float bv = bias ? bias[n] : 0.f;
            #pragma unroll
            for (int r = 0; r < 4; r++) {
                int m = bm * 128 + wr * 64 + mi * 16 + rq * 4 + r;
                float v = acc[mi][ni][r] + bv;
                if (out_mode == 1) {
                    // scan-order store: [t][wg64][lane2][r2]  (validated round 4)
                    int t = m & 1023, b = m >> 10;
                    int g_loc = n >> 9, wg64i = (n >> 3) & 63, u_loc = n & 7;
                    int lane2 = (((b >> 2) & 1) << 5) | (u_loc << 2) | g_loc;
                    int r2 = (b & 3) | ((b >> 3) << 2);
                    ((u16*)Cp)[(((size_t)t * 64 + wg64i) * 64 + lane2) * 16 + r2] = f2bf(v);
                } else {
                    ((float*)Cp)[(size_t)m * N + n] = v;
                }
            }
        }
    }
}

// ---------------- LSTM scan: 16 same-XCD WGs x 4 waves ----------------------
// Protocol identical to round 10/11 (validated: 3.35ms scan, FETCH 66MB):
// election -> intra-XCD L2 messaging; scalar-cache poll (s_dcache_inv +
// s_load_dwordx8, contention-free); one buffer_inv + plain bulk reads;
// plain h stores -> vmcnt(0) -> barrier -> per-WG flag.
// CHANGE: 16 WGs x 4 waves instead of 8 x 8 -- same 64 wave-slots spread
// over 2x the CUs, halving the per-CU MFMA serialization (256 -> 128 MFMA
// x ~8cy = 2048 -> 1024 cy/step). A 40KB LDS pad (kept alive by a volatile
// read -- r6's pad was DCE'd) forces 1 WG/CU so winners never share a
// matrix pipe.
__global__ __launch_bounds__(256, 1) void lstm_scan_kernel(
    const u16* __restrict__ xw,    // [S][64][64][16] bf16 scan-order
    const u16* __restrict__ UT,    // [4H][NH] bf16
    u16* __restrict__ hseq,        // [B][S][NH] bf16
    u16* __restrict__ hbuf,        // [2][32][512] bf16
    u32* __restrict__ flags,       // [16] per-WG progress
    u32* __restrict__ elect,       // [8] per-XCD registration counters
    int* __restrict__ winner)      // winning XCD id, init -1
{
    __shared__ int s_role;
    __shared__ u16 h_lds[32][520];      // [batch][k], +8 u16 pad (0-conflict, r2)
    __shared__ float gl[4][32][32];     // per-wave gate exchange
    __shared__ u32 lds_pad[10240];      // 40KB occupancy pad -> 1 WG/CU

    const int tid = threadIdx.x;

    // keep the pad allocated: one volatile LDS read cannot be DCE'd
    lds_pad[tid] = (u32)tid;
    {
        volatile u32* vp = lds_pad;
        u32 dummy = vp[tid];
        asm volatile("" :: "v"(dummy));
    }

    if (tid == 0) {
        u32 xcc;
        asm volatile("s_getreg_b32 %0, hwreg(HW_REG_XCC_ID)" : "=s"(xcc));
        xcc &= 7u;
        u32 r = __hip_atomic_fetch_add(&elect[xcc], 1u,
                    __ATOMIC_ACQ_REL, __HIP_MEMORY_SCOPE_AGENT);
        int role = -1;
        if (r < (u32)SC_NWG) {
            if (r == (u32)SC_NWG - 1) {   // our XCD just reached 16: try claim
                int expv = -1;
                __hip_atomic_compare_exchange_strong(winner, &expv, (int)xcc,
                    __ATOMIC_ACQ_REL, __ATOMIC_ACQUIRE, __HIP_MEMORY_SCOPE_AGENT);
            }
            int w = -1;
            for (int spins = 0; spins < 200000; spins++) {   // bounded
                w = __hip_atomic_load(winner, __ATOMIC_ACQUIRE,
                                      __HIP_MEMORY_SCOPE_AGENT);
                if (w >= 0) break;
                __builtin_amdgcn_s_sleep(8);
            }
            role = (w == (int)xcc) ? (int)r : -1;
        }
        s_role = role;
    }
    __syncthreads();
    const int role = s_role;
    if (role < 0) return;

    const int wave = tid >> 6, lane = tid & 63;
    const int wg64 = role * 4 + wave;
    const int col  = lane & 31, half = lane >> 5;
    const int u_loc = col >> 2, g_loc = col & 3;
    const int ucol  = g_loc * 512 + wg64 * 8 + u_loc;

    // U B-fragments (asm loads, r11; resident or AGPR-backed either way)
    bf16x8 ufrag[32];
    {
        const u16* ub = &UT[(size_t)ucol * 512 + half * 8];
        #define LDU4(i0)                                                      \
            asm volatile(                                                     \
                "global_load_dwordx4 %0, %4, off\n\t"                         \
                "global_load_dwordx4 %1, %4, off offset:32\n\t"               \
                "global_load_dwordx4 %2, %4, off offset:64\n\t"               \
                "global_load_dwordx4 %3, %4, off offset:96"                   \
                : "=&v"(ufrag[i0]), "=&v"(ufrag[i0 + 1]),                     \
                  "=&v"(ufrag[i0 + 2]), "=&v"(ufrag[i0 + 3])                  \
                : "v"(ub + (i0) * 16))
        LDU4(0); LDU4(4); LDU4(8); LDU4(12);
        LDU4(16); LDU4(20); LDU4(24); LDU4(28);
        #undef LDU4
        asm volatile("s_waitcnt vmcnt(0)" ::: "memory");
    }

    float cst[4] = {0.f, 0.f, 0.f, 0.f};

    // h(0) = 0 in LDS (t=0 skips the poll)
    {
        bf16x8 z = (bf16x8){0, 0, 0, 0, 0, 0, 0, 0};
        bf16x8* hf = (bf16x8*)&h_lds[0][0];
        for (int i = tid; i < 2080; i += 256) hf[i] = z;
    }

    const int sb_b  = tid >> 4;   // base row 0..15 (handles sb_b, sb_b+16)
    const int sb_ic = tid & 15;   // 16B chunk, 256B-strided (0-conflict, r2)

    for (int t = 0; t < 1024; t++) {
        // xw for this step: 32B contiguous per lane, issued early
        const u16* xp = xw + ((size_t)((size_t)t * 64 + wg64) * 64 + lane) * 16;
        bf16x8 xv0 = *(const bf16x8*)xp;
        bf16x8 xv1 = *(const bf16x8*)(xp + 8);

        if (t > 0) {
            const u32 tg = (u32)t;
            // ---- scalar-cache poll: 2 SMEM ops/wave/round, contention-free ----
            {
                u32x8 f0, f1;
                int rounds = 0;
                while (1) {
                    asm volatile("s_dcache_inv\n\t"
                                 "s_load_dwordx8 %0, %2, 0x0\n\t"
                                 "s_load_dwordx8 %1, %2, 0x20\n\t"
                                 "s_waitcnt lgkmcnt(0)"
                                 : "=s"(f0), "=s"(f1) : "s"(flags) : "memory");
                    bool ok = f0[0] >= tg && f0[1] >= tg && f0[2] >= tg &&
                              f0[3] >= tg && f0[4] >= tg && f0[5] >= tg &&
                              f0[6] >= tg && f0[7] >= tg &&
                              f1[0] >= tg && f1[1] >= tg && f1[2] >= tg &&
                              f1[3] >= tg && f1[4] >= tg && f1[5] >= tg &&
                              f1[6] >= tg && f1[7] >= tg;
                    if (ok || ++rounds > (1 << 13)) break;
                }
            }
            // one L1 invalidate, then plain bulk reads served by shared L2
            asm volatile("buffer_inv" ::: "memory");
            const char* sb0 = (const char*)(hbuf + ((size_t)(t & 1) << 14))
                              + sb_b * 1024 + sb_ic * 16;
            f32x4 r0, r1, r2, r3, r4, r5, r6, r7;
            asm volatile(
                "global_load_dwordx4 %0, %8, off\n\t"
                "global_load_dwordx4 %1, %8, off offset:256\n\t"
                "global_load_dwordx4 %2, %8, off offset:512\n\t"
                "global_load_dwordx4 %3, %8, off offset:768\n\t"
                "global_load_dwordx4 %4, %9, off\n\t"
                "global_load_dwordx4 %5, %9, off offset:256\n\t"
                "global_load_dwordx4 %6, %9, off offset:512\n\t"
                "global_load_dwordx4 %7, %9, off offset:768\n\t"
                "s_waitcnt vmcnt(0)"
                : "=&v"(r0), "=&v"(r1), "=&v"(r2), "=&v"(r3),
                  "=&v"(r4), "=&v"(r5), "=&v"(r6), "=&v"(r7)
                : "v"(sb0), "v"(sb0 + 16384) : "memory");
            __builtin_amdgcn_sched_barrier(0);
            u16* d0 = &h_lds[sb_b][sb_ic * 8];
            u16* d1 = &h_lds[sb_b + 16][sb_ic * 8];
            *(f32x4*)(d0)       = r0;
            *(f32x4*)(d0 + 128) = r1;
            *(f32x4*)(d0 + 256) = r2;
            *(f32x4*)(d0 + 384) = r3;
            *(f32x4*)(d1)       = r4;
            *(f32x4*)(d1 + 128) = r5;
            *(f32x4*)(d1 + 256) = r6;
            *(f32x4*)(d1 + 384) = r7;
        }
        __syncthreads();

        // gates = h @ Uslice: 2 accumulators halve the dependent-MFMA chain
        f32x16 a0 = {0,0,0,0, 0,0,0,0, 0,0,0,0, 0,0,0,0};
        f32x16 a1 = {0,0,0,0, 0,0,0,0, 0,0,0,0, 0,0,0,0};
        #pragma unroll
        for (int kk = 0; kk < 16; kk++) {
            bf16x8 af0 = *(const bf16x8*)&h_lds[col][kk * 16 + half * 8];
            a0 = __builtin_amdgcn_mfma_f32_32x32x16_bf16(af0, ufrag[kk], a0, 0, 0, 0);
            bf16x8 af1 = *(const bf16x8*)&h_lds[col][(kk + 16) * 16 + half * 8];
            a1 = __builtin_amdgcn_mfma_f32_32x32x16_bf16(af1, ufrag[kk + 16], a1, 0, 0, 0);
        }

        // gate exchange (wave-local LDS; in-wave lgkmcnt ordering, no barrier)
        #pragma unroll
        for (int r = 0; r < 16; r++) {
            int b = (r & 3) + ((r >> 2) << 3) + (half << 2);
            float xwv = bf2f(r < 8 ? (u16)xv0[r] : (u16)xv1[r - 8]);
            gl[wave][b][col] = a0[r] + a1[r] + xwv;
        }

        // cell update: compute 4 results, then burst plain h stores
        u16 hv[4];
        int bi[4];
        #pragma unroll
        for (int i = 0; i < 4; i++) {
            int p = (i << 6) + lane, b = p >> 3, u = p & 7;
            f32x4 g4 = *(const f32x4*)&gl[wave][b][u << 2];   // i,f,g,o
            float si = fsig(g4[0]), sf = fsig(g4[1]);
            float sg = ftanh(g4[2]), so = fsig(g4[3]);
            float c = sf * cst[i] + si * sg;
            cst[i] = c;
            hv[i] = f2bf(so * ftanh(c));
            bi[i] = b;
        }
        u16* hb_out = hbuf + ((size_t)(((size_t)t + 1) & 1) << 14);
        const int j = (wg64 << 3);
        #pragma unroll
        for (int i = 0; i < 4; i++) {
            int p = (i << 6) + lane, u = p & 7;
            u32 hw = hv[i];
            u16* hp = hb_out + bi[i] * 512 + j + u;
            asm volatile("global_store_short %0, %1, off"
                         :: "v"(hp), "v"(hw) : "memory");
        }
        // drain to shared L2, WG barrier, publish per-WG flag
        asm volatile("s_waitcnt vmcnt(0)" ::: "memory");
        __syncthreads();
        if (tid == 0) {
            u32 fv = (u32)(t + 1);
            u32* fq = flags + role;
            asm volatile("global_store_dword %0, %1, off"
                         :: "v"(fq), "v"(fv) : "memory");
        }
        // hseq: plain cached stores, off the critical path
        #pragma unroll
        for (int i = 0; i < 4; i++) {
            int p = (i << 6) + lane, u = p & 7;
            hseq[((size_t)bi[i] * S_ + t) * NH_ + j + u] = hv[i];
        }
    }
}

extern "C" void kernel_launch(void* const* d_in, const int* in_sizes, int n_in,
                              void* d_out, int out_size, void* d_ws, size_t ws_size,
                              hipStream_t stream) {
    const float* x        = (const float*)d_in[0];
    const float* W        = (const float*)d_in[1];
    const float* U        = (const float*)d_in[2];
    const float* hid_bias = (const float*)d_in[3];
    const float* V        = (const float*)d_in[4];
    const float* out_bias = (const float*)d_in[5];

    char* ws = (char*)d_ws;
    size_t off = 0;
    auto carve = [&](size_t bytes) -> void* {
        void* p = ws + off;
        off += (bytes + 255) & ~(size_t)255;
        return p;
    };
    u16* xw     = (u16*)carve((size_t)B_ * S_ * G4_ * 2);   // 128 MB, scan-order
    u16* xbf    = (u16*)carve((size_t)B_ * S_ * NH_ * 2);   //  32 MB
    u16* hseq   = (u16*)carve((size_t)B_ * S_ * NH_ * 2);   //  32 MB
    u16* WT     = (u16*)carve((size_t)G4_ * NH_ * 2);       //   2 MB
    u16* UT     = (u16*)carve((size_t)G4_ * NH_ * 2);       //   2 MB
    u16* VT     = (u16*)carve((size_t)NH_ * NH_ * 2);       // 512 KB
    u16* hbuf   = (u16*)carve((size_t)2 * B_ * NH_ * 2);    //  64 KB
    u32* flags  = (u32*)carve(256);
    u32* elect  = (u32*)carve(256);
    int* winner = (int*)carve(256);

    hipMemsetAsync(flags, 0, 256, stream);
    hipMemsetAsync(elect, 0, 256, stream);
    hipMemsetAsync(winner, 0xFF, 256, stream);   // winner = -1

    int n4 = B_ * S_ * NH_ / 4;
    cvt_bf16_kernel<<<(n4 + 255) / 256, 256, 0, stream>>>(x, xbf, n4);
    transpose_cvt_kernel<<<dim3(G4_ / 32, NH_ / 32), 256, 0, stream>>>(W, WT, NH_, G4_);
    transpose_cvt_kernel<<<dim3(G4_ / 32, NH_ / 32), 256, 0, stream>>>(U, UT, NH_, G4_);
    transpose_cvt_kernel<<<dim3(NH_ / 32, NH_ / 32), 256, 0, stream>>>(V, VT, NH_, NH_);

    // xW + hid_bias -> bf16, stored in scan order
    gemm_bf16_kernel<<<4096, 256, 0, stream>>>(xbf, WT, hid_bias, xw,
                                               B_ * S_, G4_, NH_, 1);
    // sequential LSTM scan (same-XCD election inside)
    lstm_scan_kernel<<<CAND, 256, 0, stream>>>(xw, UT, hseq, hbuf,
                                               flags, elect, winner);
    // out = hseq @ V + out_bias -> f32
    gemm_bf16_kernel<<<1024, 256, 0, stream>>>(hseq, VT, out_bias, d_out,
                                               B_ * S_, NH_, NH_, 0);
}